// Round 3
// baseline (217.431 us; speedup 1.0000x reference)
//
#include <hip/hip_runtime.h>
#include <math.h>

#define NUM_GRAPHS 512
#define D 128
#define NEG 0.01f
#define BN 64   // nodes per tile / block in MFMA MLP kernel

typedef __attribute__((ext_vector_type(8))) short  bf16x8;  // MFMA A/B frag
typedef __attribute__((ext_vector_type(4))) float  f32x4;   // MFMA C/D frag

__device__ __forceinline__ unsigned short f2bf(float f) {
    unsigned u = __float_as_uint(f);
    u += 0x7fffu + ((u >> 16) & 1u);   // RNE
    return (unsigned short)(u >> 16);
}

// swizzled ushort index within a 64x256 tile: row*256 + (k ^ ((row&7)<<3))
__device__ __forceinline__ int swz(int row, int k) {
    return row * 256 + (k ^ ((row & 7) << 3));
}

#define GLD16(gsrc, ldst)                                                    \
    __builtin_amdgcn_global_load_lds(                                        \
        (const __attribute__((address_space(1))) void*)(gsrc),               \
        (__attribute__((address_space(3))) void*)(ldst), 16, 0, 0)

// ---------------------------------------------------------------------------
// Kernel 1: per-graph segment max+mean AND bf16 tile-blocked pre-swizzled copy
// of X. grid=(NUM_GRAPHS,2) [y:0=topo,1=geom], block=256.
// pooled[g*512 + t*256 + {0..127:max,128..255:mean}]
// xt: per 64-node tile, 64*256 ushorts, element (r,k) at swz(r,k);
//     topo -> k 0..127, geom -> k 128..255.
// ---------------------------------------------------------------------------
__global__ __launch_bounds__(256) void pool_kernel(
    const float* __restrict__ h_topo, const float* __restrict__ h_geom,
    const int* __restrict__ batch, int N, float* __restrict__ pooled,
    unsigned short* __restrict__ xt)
{
    const int g = blockIdx.x, t = blockIdx.y;
    const float* __restrict__ h = t ? h_geom : h_topo;
    const int koff = t ? 128 : 0;

    int lo = 0, hi = N;
    while (lo < hi) { int m = (lo + hi) >> 1; if (batch[m] < g) lo = m + 1; else hi = m; }
    const int start = lo; hi = N;
    while (lo < hi) { int m = (lo + hi) >> 1; if (batch[m] < g + 1) lo = m + 1; else hi = m; }
    const int end = lo;

    const int c = threadIdx.x & 31;   // float4 column
    const int r = threadIdx.x >> 5;   // 0..7 row phase
    const int kk = koff + c * 4;

    float4 mx = make_float4(-INFINITY, -INFINITY, -INFINITY, -INFINITY);
    float4 sm = make_float4(0.f, 0.f, 0.f, 0.f);
    for (int row = start + r; row < end; row += 8) {
        float4 v = *(const float4*)(h + (size_t)row * D + c * 4);
        mx.x = fmaxf(mx.x, v.x); mx.y = fmaxf(mx.y, v.y);
        mx.z = fmaxf(mx.z, v.z); mx.w = fmaxf(mx.w, v.w);
        sm.x += v.x; sm.y += v.y; sm.z += v.z; sm.w += v.w;

        // bf16 pre-swizzled tile copy
        uint2 pk;
        pk.x = (unsigned)f2bf(v.x) | ((unsigned)f2bf(v.y) << 16);
        pk.y = (unsigned)f2bf(v.z) | ((unsigned)f2bf(v.w) << 16);
        const int tile = row >> 6, rl = row & 63;
        *(uint2*)(xt + (size_t)tile * 16384 + swz(rl, kk)) = pk;
    }

    __shared__ float4 smx[256], ssm[256];
    smx[threadIdx.x] = mx; ssm[threadIdx.x] = sm;
    __syncthreads();
    #pragma unroll
    for (int s = 4; s > 0; s >>= 1) {
        if (r < s) {
            float4 a = smx[threadIdx.x + s * 32];
            float4 b = ssm[threadIdx.x + s * 32];
            float4 m0 = smx[threadIdx.x];
            float4 s0 = ssm[threadIdx.x];
            m0.x = fmaxf(m0.x, a.x); m0.y = fmaxf(m0.y, a.y);
            m0.z = fmaxf(m0.z, a.z); m0.w = fmaxf(m0.w, a.w);
            s0.x += b.x; s0.y += b.y; s0.z += b.z; s0.w += b.w;
            smx[threadIdx.x] = m0; ssm[threadIdx.x] = s0;
        }
        __syncthreads();
    }
    if (r == 0) {
        float4 m0 = smx[threadIdx.x], s0 = ssm[threadIdx.x];
        const float inv = 1.0f / fmaxf((float)(end - start), 1.0f);
        float4 mean = make_float4(s0.x * inv, s0.y * inv, s0.z * inv, s0.w * inv);
        if (end <= start) { m0 = make_float4(0,0,0,0); mean = make_float4(0,0,0,0); }
        float* dst = pooled + (size_t)g * 512 + t * 256;
        *(float4*)(dst + c * 4)       = m0;
        *(float4*)(dst + 128 + c * 4) = mean;
    }
}

// ---------------------------------------------------------------------------
// Kernel 2: per-graph bias P[g][j] = b1[j] + pooled[g] . W1[pooled rows][j]
// ---------------------------------------------------------------------------
__global__ __launch_bounds__(256) void pmat_kernel(
    const float* __restrict__ pooled, const float* __restrict__ W1,
    const float* __restrict__ b1, float* __restrict__ P)
{
    const int g = blockIdx.x;
    const int j = threadIdx.x;

    __shared__ float pl[512];
    pl[j]       = pooled[(size_t)g * 512 + j];
    pl[j + 256] = pooled[(size_t)g * 512 + 256 + j];
    __syncthreads();

    float acc = b1[j];
    #pragma unroll 8
    for (int k = 0; k < 256; ++k)          // t_max,t_mean -> W1 rows 128..383
        acc += pl[k] * W1[(size_t)(128 + k) * 256 + j];
    #pragma unroll 8
    for (int k = 0; k < 256; ++k)          // g_max,g_mean -> W1 rows 512..767
        acc += pl[256 + k] * W1[(size_t)(512 + k) * 256 + j];

    P[(size_t)g * 256 + j] = acc;
}

// ---------------------------------------------------------------------------
// Kernel 3: weight pre-convert to transposed bf16.
// W1bT[n][k] = bf16(W1[kmap(k)][n]), kmap(k) = k<128 ? k : k+256
// W2bT[n][k] = bf16(W2[k][n])
// ---------------------------------------------------------------------------
__global__ __launch_bounds__(256) void wconv_kernel(
    const float* __restrict__ W1, const float* __restrict__ W2,
    unsigned short* __restrict__ W1bT, unsigned short* __restrict__ W2bT)
{
    const int idx = blockIdx.x * 256 + threadIdx.x;
    if (idx < 256 * 256) {
        const int n = idx >> 8, k = idx & 255;
        const int kk = (k < 128) ? k : (k + 256);
        W1bT[idx] = f2bf(W1[(size_t)kk * 256 + n]);
    } else {
        const int j = idx - 256 * 256;
        if (j < 128 * 256) {
            const int n = j >> 8, k = j & 255;
            W2bT[j] = f2bf(W2[(size_t)k * 128 + n]);
        }
    }
}

// ---------------------------------------------------------------------------
// Kernel 4: fused MFMA MLP, DMA-staged.
//  - stage: 8x global_load_lds(16B) per wave, xt tile -> LDS (linear both sides,
//    source is pre-swizzled so LDS holds swz layout)
//  - GEMM1 [64x256 @ 256x256], acc C-in = P broadcast (uniform-graph fast path)
//  - LeakyReLU -> bf16 H over X in LDS
//  - GEMM2 [64x256 @ 256x128] + b2 -> out (f32)
// MFMA 16x16x32 frags: A row=l&15 k=(l>>4)*8+j; B col=l&15; D col=l&15,row=(l>>4)*4+q.
// ---------------------------------------------------------------------------
__global__ __launch_bounds__(256, 4) void mlp_mfma(
    const unsigned short* __restrict__ xt, const int* __restrict__ batch,
    const float* __restrict__ P,
    const unsigned short* __restrict__ W1bT, const unsigned short* __restrict__ W2bT,
    const float* __restrict__ b2, float* __restrict__ out, int N)
{
    __shared__ unsigned short xs[64 * 256];   // 32 KB, X then H (swz layout)
    __shared__ int gid[64];

    const int tid  = threadIdx.x;
    const int wave = tid >> 6, lane = tid & 63;
    const int base = blockIdx.x * BN;
    const size_t tbase = (size_t)blockIdx.x * 16384;

    // ---- DMA stage: tile -> LDS, linear copy (2048 x 16B total) ----
    #pragma unroll
    for (int c = 0; c < 8; ++c) {
        const int off = wave * 4096 + c * 512;           // ushort units
        GLD16(xt + tbase + off + lane * 8, xs + off);
    }
    if (tid < 64) gid[tid] = batch[min(base + tid, N - 1)];

    // uniform-graph fast path? (batch sorted -> endpoints equal => all equal)
    const int g0 = batch[base];
    const int g1 = batch[min(base + 63, N - 1)];
    const bool uni = (g0 == g1);

    const int lhi = lane >> 4;   // 0..3
    const int llo = lane & 15;   // 0..15

    float pf[4];
    if (uni) {
        #pragma unroll
        for (int ct = 0; ct < 4; ++ct)
            pf[ct] = P[(size_t)g0 * 256 + wave * 64 + ct * 16 + llo];
    }

    asm volatile("s_waitcnt vmcnt(0)" ::: "memory");
    __syncthreads();

    // ---- GEMM1 ----
    f32x4 acc[4][4];
    #pragma unroll
    for (int rt = 0; rt < 4; ++rt)
        #pragma unroll
        for (int ct = 0; ct < 4; ++ct) {
            const float p = uni ? pf[ct] : 0.f;
            acc[rt][ct] = (f32x4){p, p, p, p};
        }

    #pragma unroll
    for (int ks = 0; ks < 8; ++ks) {
        const int kb = ks * 32 + lhi * 8;
        bf16x8 afr[4], bfr[4];
        #pragma unroll
        for (int rt = 0; rt < 4; ++rt)
            afr[rt] = *(const bf16x8*)&xs[swz(rt * 16 + llo, kb)];
        #pragma unroll
        for (int ct = 0; ct < 4; ++ct)
            bfr[ct] = *(const bf16x8*)(W1bT + (size_t)(wave * 64 + ct * 16 + llo) * 256 + kb);
        #pragma unroll
        for (int rt = 0; rt < 4; ++rt)
            #pragma unroll
            for (int ct = 0; ct < 4; ++ct)
                acc[rt][ct] = __builtin_amdgcn_mfma_f32_16x16x32_bf16(
                    afr[rt], bfr[ct], acc[rt][ct], 0, 0, 0);
    }
    __syncthreads();   // all waves done reading X

    // ---- epilogue 1: (+P if boundary tile), LeakyReLU, H -> LDS (bf16) ----
    #pragma unroll
    for (int rt = 0; rt < 4; ++rt) {
        #pragma unroll
        for (int ct = 0; ct < 4; ++ct) {
            const int col = wave * 64 + ct * 16 + llo;
            #pragma unroll
            for (int q = 0; q < 4; ++q) {
                const int row = rt * 16 + lhi * 4 + q;
                float v = acc[rt][ct][q];
                if (!uni) v += P[(size_t)gid[row] * 256 + col];
                v = (v >= 0.f) ? v : NEG * v;
                xs[swz(row, col)] = f2bf(v);
            }
        }
    }
    __syncthreads();

    // ---- GEMM2 ----
    f32x4 acc2[4][2];
    #pragma unroll
    for (int ct = 0; ct < 2; ++ct) {
        const float bv = b2[wave * 32 + ct * 16 + llo];
        #pragma unroll
        for (int rt = 0; rt < 4; ++rt)
            acc2[rt][ct] = (f32x4){bv, bv, bv, bv};
    }
    #pragma unroll
    for (int ks = 0; ks < 8; ++ks) {
        const int kb = ks * 32 + lhi * 8;
        bf16x8 afr[4], bfr[2];
        #pragma unroll
        for (int rt = 0; rt < 4; ++rt)
            afr[rt] = *(const bf16x8*)&xs[swz(rt * 16 + llo, kb)];
        #pragma unroll
        for (int ct = 0; ct < 2; ++ct)
            bfr[ct] = *(const bf16x8*)(W2bT + (size_t)(wave * 32 + ct * 16 + llo) * 256 + kb);
        #pragma unroll
        for (int rt = 0; rt < 4; ++rt)
            #pragma unroll
            for (int ct = 0; ct < 2; ++ct)
                acc2[rt][ct] = __builtin_amdgcn_mfma_f32_16x16x32_bf16(
                    afr[rt], bfr[ct], acc2[rt][ct], 0, 0, 0);
    }

    // ---- store out (f32) ----
    #pragma unroll
    for (int rt = 0; rt < 4; ++rt)
        #pragma unroll
        for (int ct = 0; ct < 2; ++ct)
            #pragma unroll
            for (int q = 0; q < 4; ++q) {
                const int row  = rt * 16 + lhi * 4 + q;
                const int node = base + row;
                if (node < N)
                    out[(size_t)node * 128 + wave * 32 + ct * 16 + llo] = acc2[rt][ct][q];
            }
}

// ---------------------------------------------------------------------------
extern "C" void kernel_launch(void* const* d_in, const int* in_sizes, int n_in,
                              void* d_out, int out_size, void* d_ws, size_t ws_size,
                              hipStream_t stream)
{
    const float* h_topo = (const float*)d_in[0];
    const float* h_geom = (const float*)d_in[1];
    const int*   batch  = (const int*)  d_in[2];
    const float* W1     = (const float*)d_in[3];
    const float* b1     = (const float*)d_in[4];
    const float* W2     = (const float*)d_in[5];
    const float* b2     = (const float*)d_in[6];
    float* out = (float*)d_out;

    const int N = in_sizes[0] / D;   // 200000

    float*          pooled = (float*)d_ws;                          // 512*512 f32
    float*          P      = pooled + (size_t)NUM_GRAPHS * 512;     // 512*256 f32
    unsigned short* W1bT   = (unsigned short*)(P + (size_t)NUM_GRAPHS * 256);
    unsigned short* W2bT   = W1bT + 256 * 256;

    const size_t small_bytes = (size_t)(NUM_GRAPHS * 512 + NUM_GRAPHS * 256) * 4
                             + (size_t)(256 * 256 + 128 * 256) * 2;   // ~1.7 MB
    const size_t xt_bytes = (size_t)N * 256 * 2;                       // 102.4 MB

    // xt: pre-swizzled bf16 tile copy of X. Prefer ws; else alias d_out
    // (tile t's xt bytes == tile t's out bytes; mlp reads them fully at the
    //  first barrier, writes only in the final store -> per-block safe, and
    //  pool regenerates xt every call).
    unsigned short* xt;
    if (ws_size >= small_bytes + xt_bytes)
        xt = (unsigned short*)((char*)d_ws + small_bytes);
    else
        xt = (unsigned short*)d_out;

    wconv_kernel<<<(256 * 256 + 128 * 256) / 256, 256, 0, stream>>>(W1, W2, W1bT, W2bT);
    pool_kernel<<<dim3(NUM_GRAPHS, 2), 256, 0, stream>>>(h_topo, h_geom, batch, N,
                                                         pooled, xt);
    pmat_kernel<<<NUM_GRAPHS, 256, 0, stream>>>(pooled, W1, b1, P);
    mlp_mfma<<<N / BN, 256, 0, stream>>>(xt, batch, P, W1bT, W2bT, b2, out, N);
}